// Round 1
// baseline (274.871 us; speedup 1.0000x reference)
//
#include <hip/hip_runtime.h>

// Problem constants: B=32 graphs, N=1024 nodes/graph, F=64, D=128, DEG=8
#define E_TOTAL 262144     // B*N*DEG
#define NGRAPH  32
#define EPG     8192       // edges per graph
#define EPS_BN  1e-5f
#define MB (1u << 20)
#define KB (1u << 10)

__device__ __forceinline__ float lrelu(float x){ return x > 0.f ? x : 0.2f * x; }

// XCD-aware block swizzle: hw round-robins blockIdx%8 across the 8 XCDs; remap so
// XCD k processes a CONTIGUOUS chunk of logical blocks (graph-locality in its L2).
// Requires grid % 8 == 0 (all our grids are).
__device__ __forceinline__ int xcd_swz(int b, int n){ return (b & 7) * (n >> 3) + (b >> 3); }

// ---------------- GEMM + attention terms: C = bn(A) @ W, es = C.a_s, ed = C.a_d ----------
// block 256 = 64 channel-pairs x 4 row-groups (one wave per row-group); 32 rows/block.
// A tile staged TRANSPOSED in LDS (stride 36 => aligned float4 broadcast reads).
// bnsums != nullptr: normalize A columns with batch stats (sums[c], sums[K+c]).
// Epilogue: row r's 128 channels live in wave rg's 64 lanes -> shuffle-reduce es/ed.
// XCD-swizzled so graph g's output rows land in the same XCD L2 that gat_pool gathers from.
template<int K>
__global__ __launch_bounds__(256)
void gemm_attn(const float* __restrict__ A, const float* __restrict__ W,
               const float* __restrict__ bnsums, float invM,
               const float* __restrict__ a_s, const float* __restrict__ a_d,
               float* __restrict__ C, float* __restrict__ es, float* __restrict__ ed){
  __shared__ float Ws[64 * 128];    // 32 KB
  __shared__ float As_t[64 * 36];   // 9 KB, [kk][row] padded
  __shared__ float bnmu[K], bnrs[K];
  int tid = threadIdx.x;
  if (tid < K){
    float mu = 0.f, rs = 1.f;
    if (bnsums){
      mu = bnsums[tid] * invM;
      float var = bnsums[K + tid] * invM - mu * mu;
      rs = rsqrtf(var + EPS_BN);
    }
    bnmu[tid] = mu; bnrs[tid] = rs;
  }
  int bid = xcd_swz(blockIdx.x, gridDim.x);
  int row0 = bid * 32;
  int c2 = tid & 63, rg = tid >> 6;
  float2 acc[8];
  #pragma unroll
  for (int i = 0; i < 8; ++i){ acc[i].x = 0.f; acc[i].y = 0.f; }

  for (int k0 = 0; k0 < K; k0 += 64){
    __syncthreads();
    for (int i = tid; i < 64 * 128; i += 256)
      Ws[i] = W[(size_t)(k0 + (i >> 7)) * 128 + (i & 127)];
    #pragma unroll
    for (int it = 0; it < 8; ++it){
      int i = it * 256 + tid;
      int r = i >> 6, kk = i & 63;
      float v = A[(size_t)(row0 + r) * K + k0 + kk];
      v = (v - bnmu[k0 + kk]) * bnrs[k0 + kk];
      As_t[kk * 36 + r] = v;
    }
    __syncthreads();
    #pragma unroll 8
    for (int kk = 0; kk < 64; ++kk){
      float2 w = *(float2*)&Ws[kk * 128 + c2 * 2];
      float4 a0 = *(float4*)&As_t[kk * 36 + rg * 8];
      float4 a1 = *(float4*)&As_t[kk * 36 + rg * 8 + 4];
      acc[0].x = fmaf(a0.x, w.x, acc[0].x); acc[0].y = fmaf(a0.x, w.y, acc[0].y);
      acc[1].x = fmaf(a0.y, w.x, acc[1].x); acc[1].y = fmaf(a0.y, w.y, acc[1].y);
      acc[2].x = fmaf(a0.z, w.x, acc[2].x); acc[2].y = fmaf(a0.z, w.y, acc[2].y);
      acc[3].x = fmaf(a0.w, w.x, acc[3].x); acc[3].y = fmaf(a0.w, w.y, acc[3].y);
      acc[4].x = fmaf(a1.x, w.x, acc[4].x); acc[4].y = fmaf(a1.x, w.y, acc[4].y);
      acc[5].x = fmaf(a1.y, w.x, acc[5].x); acc[5].y = fmaf(a1.y, w.y, acc[5].y);
      acc[6].x = fmaf(a1.z, w.x, acc[6].x); acc[6].y = fmaf(a1.z, w.y, acc[6].y);
      acc[7].x = fmaf(a1.w, w.x, acc[7].x); acc[7].y = fmaf(a1.w, w.y, acc[7].y);
    }
  }
  float2 as2 = ((const float2*)a_s)[c2];
  float2 ad2 = ((const float2*)a_d)[c2];
  float2* C2 = (float2*)C;
  #pragma unroll
  for (int i = 0; i < 8; ++i){
    int r = row0 + rg * 8 + i;
    C2[(size_t)r * 64 + c2] = acc[i];
    float e1 = acc[i].x * as2.x + acc[i].y * as2.y;
    float e2 = acc[i].x * ad2.x + acc[i].y * ad2.y;
    #pragma unroll
    for (int o = 32; o; o >>= 1){ e1 += __shfl_xor(e1, o); e2 += __shfl_xor(e2, o); }
    if (c2 == 0){ es[r] = e1; ed[r] = e2; }
  }
}

// ---------------- edge preprocessing: ALL 3 layers' CSRs in 3 wide kernels -------------
// The CSR/mask chain depends only on edge_index (not on features), and the dedupe masks
// are computable edge-locally: mask2 = act1 && s2!=d2 && first-claim(bitmap0);
// mask3 = mask2 && s3!=d3 && first-claim(bitmap1). So instead of 3 serialized 32-block
// sorts, run one 256-block count pass + 96-block scan + one 256-block scatter pass.
// 8 blocks per graph, 1 edge per thread. cnt buffers double as gat_pool's row_cnt.
__global__ __launch_bounds__(1024)
void csr_count_all(const int* __restrict__ src0, const int* __restrict__ dst0,
                   int* __restrict__ cnt1, int* __restrict__ cnt2, int* __restrict__ cnt3,
                   unsigned char* __restrict__ mask2, unsigned char* __restrict__ mask3,
                   unsigned int* __restrict__ bitmap0, unsigned int* __restrict__ bitmap1){
  __shared__ int h1[1024];
  __shared__ int h2[512];
  __shared__ int h3[256];
  int lb = xcd_swz(blockIdx.x, gridDim.x);
  int g = lb >> 3, sub = lb & 7;
  int t = threadIdx.x;
  h1[t] = 0;
  if (t < 512) h2[t] = 0;
  if (t < 256) h3[t] = 0;
  __syncthreads();
  int e = g * EPG + sub * 1024 + t;
  int sv = src0[e], dv = dst0[e];
  unsigned char m2 = 0, m3 = 0;
  if (sv != dv){
    atomicAdd(&h1[dv & 1023], 1);
    int s2 = sv >> 1, d2 = dv >> 1;
    if (s2 != d2){
      unsigned int key = ((unsigned int)(s2 >> 9) << 18) |
                         ((unsigned int)(s2 & 511) << 9) | (unsigned int)(d2 & 511);
      unsigned int bit = 1u << (key & 31u);
      unsigned int old = atomicOr(&bitmap0[key >> 5], bit);
      m2 = (old & bit) ? 0 : 1;
    }
  }
  if (m2){
    atomicAdd(&h2[(dv >> 1) & 511], 1);
    int s3 = sv >> 2, d3 = dv >> 2;
    if (s3 != d3){
      unsigned int key = ((unsigned int)(s3 >> 8) << 16) |
                         ((unsigned int)(s3 & 255) << 8) | (unsigned int)(d3 & 255);
      unsigned int bit = 1u << (key & 31u);
      unsigned int old = atomicOr(&bitmap1[key >> 5], bit);
      m3 = (old & bit) ? 0 : 1;
    }
  }
  if (m3) atomicAdd(&h3[(dv >> 2) & 255], 1);
  mask2[e] = m2; mask3[e] = m3;
  __syncthreads();
  if (h1[t])            atomicAdd(&cnt1[(g << 10) + t], h1[t]);
  if (t < 512 && h2[t]) atomicAdd(&cnt2[(g << 9) + t],  h2[t]);
  if (t < 256 && h3[t]) atomicAdd(&cnt3[(g << 8) + t],  h3[t]);
}

// 96 blocks = 3 layers x 32 graphs: exclusive scan of one graph's histogram ->
// absolute row_start into that layer's csr buffer, plus the scatter cursor array.
__global__ __launch_bounds__(1024)
void csr_scan3(const int* __restrict__ cnt1, const int* __restrict__ cnt2,
               const int* __restrict__ cnt3,
               int* __restrict__ rs1, int* __restrict__ rs2, int* __restrict__ rs3,
               int* __restrict__ pos1, int* __restrict__ pos2, int* __restrict__ pos3){
  __shared__ int wsum[16];
  int b = blockIdx.x;
  int l = b >> 5, g = b & 31;
  const int* cnt = (l == 0) ? cnt1 : (l == 1) ? cnt2 : cnt3;
  int* rs = (l == 0) ? rs1 : (l == 1) ? rs2 : rs3;
  int* pp = (l == 0) ? pos1 : (l == 1) ? pos2 : pos3;
  int Npg = 1024 >> l;
  int t = threadIdx.x;
  int c = (t < Npg) ? cnt[g * Npg + t] : 0;
  int lane = t & 63, w = t >> 6;
  int v = c;
  #pragma unroll
  for (int o = 1; o < 64; o <<= 1){
    int u = __shfl_up(v, o);
    if (lane >= o) v += u;
  }
  if (lane == 63) wsum[w] = v;
  __syncthreads();
  if (t == 0){
    int run = 0;
    #pragma unroll
    for (int i = 0; i < 16; ++i){ int x = wsum[i]; wsum[i] = run; run += x; }
  }
  __syncthreads();
  int excl = v - c + wsum[w];
  if (t < Npg){
    int p = g * EPG + excl;
    rs[g * Npg + t] = p;
    pp[g * Npg + t] = p;
  }
}

__global__ __launch_bounds__(1024)
void csr_scatter_all(const int* __restrict__ src0, const int* __restrict__ dst0,
                     const unsigned char* __restrict__ mask2,
                     const unsigned char* __restrict__ mask3,
                     int* __restrict__ pos1, int* __restrict__ pos2, int* __restrict__ pos3,
                     int* __restrict__ csr1, int* __restrict__ csr2, int* __restrict__ csr3){
  int lb = xcd_swz(blockIdx.x, gridDim.x);
  int g = lb >> 3, sub = lb & 7;
  int t = threadIdx.x;
  int e = g * EPG + sub * 1024 + t;
  int sv = src0[e], dv = dst0[e];
  if (sv != dv){
    int p = atomicAdd(&pos1[(g << 10) + (dv & 1023)], 1);
    csr1[p] = sv;
  }
  if (mask2[e]){
    int p = atomicAdd(&pos2[(g << 9) + ((dv >> 1) & 511)], 1);
    csr2[p] = sv >> 1;
  }
  if (mask3[e]){
    int p = atomicAdd(&pos3[(g << 8) + ((dv >> 2) & 255)], 1);
    csr3[p] = sv >> 2;
  }
}

// ---------------- GAT softmax-aggregate + bias + ReLU + pairwise max-pool ----------------
// one wave per dst node; block 256 -> nodes 4b..4b+3 = pool pairs; writes M/2 pooled rows.
// XCD-swizzled with the same graph->XCD map as gemm_attn: gathers hit the local L2.
__global__ void gat_pool(const float* __restrict__ h, const float* __restrict__ es,
                         const float* __restrict__ ed, const int* __restrict__ csr_src,
                         const int* __restrict__ row_start, const int* __restrict__ row_cnt,
                         const float* __restrict__ bias, float* __restrict__ xout, int M){
  __shared__ float2 osh[4][64];
  int lane = threadIdx.x & 63;
  int wave = threadIdx.x >> 6;
  int bid = xcd_swz(blockIdx.x, gridDim.x);
  int n = bid * 4 + wave;
  int start = row_start[n];
  int cnt   = row_cnt[n];
  float edn = ed[n];
  float selfl = lrelu(es[n] + edn);

  // phase A: online softmax stats, lane-parallel
  float m_l = -1e30f, d_l = 0.f;
  for (int c0 = 0; c0 < cnt; c0 += 64){
    int j = c0 + lane;
    if (j < cnt){
      int s = csr_src[start + j];
      float l = lrelu(es[s] + edn);
      float mn = fmaxf(m_l, l);
      d_l = d_l * __expf(m_l - mn) + __expf(l - mn);
      m_l = mn;
    }
  }
  #pragma unroll
  for (int o = 32; o; o >>= 1){
    float m2 = __shfl_xor(m_l, o), d2 = __shfl_xor(d_l, o);
    float mn = fmaxf(m_l, m2);
    d_l = d_l * __expf(m_l - mn) + d2 * __expf(m2 - mn);
    m_l = mn;
  }
  float mf  = fmaxf(m_l, selfl);
  float den = d_l * __expf(m_l - mf) + __expf(selfl - mf);

  // phase B: weighted accumulation, 8 gathers in flight via shfl-broadcast indices
  const float2* h2 = (const float2*)h;
  float sw = __expf(selfl - mf);
  float2 hv = h2[(size_t)n * 64 + lane];
  float2 acc; acc.x = sw * hv.x; acc.y = sw * hv.y;
  for (int c0 = 0; c0 < cnt; c0 += 64){
    int j = c0 + lane;
    int s_j = 0; float w_j = 0.f;
    if (j < cnt){
      s_j = csr_src[start + j];
      w_j = __expf(lrelu(es[s_j] + edn) - mf);
    }
    int rem = min(64, cnt - c0);
    int k = 0;
    for (; k + 8 <= rem; k += 8){
      int ss[8]; float ww[8]; float2 hh[8];
      #pragma unroll
      for (int i = 0; i < 8; ++i){ ss[i] = __shfl(s_j, k + i); ww[i] = __shfl(w_j, k + i); }
      #pragma unroll
      for (int i = 0; i < 8; ++i){ hh[i] = h2[(size_t)ss[i] * 64 + lane]; }
      #pragma unroll
      for (int i = 0; i < 8; ++i){
        acc.x = fmaf(ww[i], hh[i].x, acc.x);
        acc.y = fmaf(ww[i], hh[i].y, acc.y);
      }
    }
    for (; k < rem; ++k){
      int s = __shfl(s_j, k); float w = __shfl(w_j, k);
      float2 hh = h2[(size_t)s * 64 + lane];
      acc.x = fmaf(w, hh.x, acc.x);
      acc.y = fmaf(w, hh.y, acc.y);
    }
  }
  float inv = 1.f / den;
  float2 bv = ((const float2*)bias)[lane];
  float2 o2;
  o2.x = fmaxf(acc.x * inv + bv.x, 0.f);
  o2.y = fmaxf(acc.y * inv + bv.y, 0.f);
  osh[wave][lane] = o2;
  __syncthreads();
  if (wave < 2){
    float2 a = osh[2 * wave][lane], b = osh[2 * wave + 1][lane];
    float2 p; p.x = fmaxf(a.x, b.x); p.y = fmaxf(a.y, b.y);
    ((float2*)xout)[(size_t)(bid * 2 + wave) * 64 + lane] = p;
  }
}

// ---------------- BN stats over pooled X ----------------
__global__ void bn_stats(const float* __restrict__ x, float* __restrict__ sums, int M){
  __shared__ float s1[256], s2[256];
  int c = threadIdx.x & 127, half = threadIdx.x >> 7;
  float a = 0.f, b = 0.f;
  for (int r = blockIdx.x * 2 + half; r < M; r += 256){
    float v = x[(size_t)r * 128 + c];
    a += v; b += v * v;
  }
  s1[threadIdx.x] = a; s2[threadIdx.x] = b;
  __syncthreads();
  if (threadIdx.x < 128){
    atomicAdd(&sums[c],       s1[threadIdx.x] + s1[threadIdx.x + 128]);
    atomicAdd(&sums[128 + c], s2[threadIdx.x] + s2[threadIdx.x + 128]);
  }
}

// ---------------- final BatchNorm apply ----------------
__global__ void bn_norm(const float* __restrict__ in, const float* __restrict__ sums,
                        float* __restrict__ out, int M){
  int idx = blockIdx.x * blockDim.x + threadIdx.x;
  if (idx >= M * 128) return;
  int c = idx & 127;
  float mu  = sums[c] / (float)M;
  float var = sums[128 + c] / (float)M - mu * mu;
  out[idx] = (in[idx] - mu) * rsqrtf(var + EPS_BN);
}

extern "C" void kernel_launch(void* const* d_in, const int* in_sizes, int n_in,
                              void* d_out, int out_size, void* d_ws, size_t ws_size,
                              hipStream_t stream){
  const float* x0   = (const float*)d_in[0];
  const float* W0   = (const float*)d_in[1];
  const float* W1   = (const float*)d_in[2];
  const float* W2   = (const float*)d_in[3];
  const float* attS = (const float*)d_in[4];
  const float* attD = (const float*)d_in[5];
  const float* bias = (const float*)d_in[6];
  const int*   src0 = (const int*)d_in[7];
  const int*   dst0 = src0 + E_TOTAL;
  float* out = (float*)d_out;                  // (32, 16384) f32

  char* ws = (char*)d_ws;
  float*         Hbuf  = (float*)(ws);                        // 16 MB
  float*         Xbuf  = (float*)(ws + 16 * MB);              //  8 MB (pooled)
  int*           csr1  = (int*)  (ws + 24 * MB);              //  1 MB
  int*           csr2  = (int*)  (ws + 25 * MB);              //  1 MB
  int*           csr3  = (int*)  (ws + 26 * MB);              //  1 MB
  float*         es    = (float*)(ws + 27 * MB);              // 128 KB
  float*         ed    = (float*)(ws + 27 * MB + 128 * KB);   // 128 KB
  int*           rs1   = (int*)  (ws + 27 * MB + 256 * KB);   // 128 KB
  int*           rs2   = (int*)  (ws + 27 * MB + 384 * KB);   //  64 KB
  int*           rs3   = (int*)  (ws + 27 * MB + 448 * KB);   //  32 KB
  int*           pos1  = (int*)  (ws + 27 * MB + 480 * KB);   // 128 KB
  int*           pos2  = (int*)  (ws + 27 * MB + 608 * KB);   //  64 KB
  int*           pos3  = (int*)  (ws + 27 * MB + 672 * KB);   //  32 KB
  unsigned char* mask2 = (unsigned char*)(ws + 28 * MB);          // 256 KB
  unsigned char* mask3 = (unsigned char*)(ws + 28 * MB + 256 * KB);// 256 KB
  // ---- zero-init region (one contiguous memset) starting at 29 MB ----
  char* zbase = ws + 29 * MB;
  int*           cnt1    = (int*)(zbase);                     // 128 KB (= row_cnt L1)
  int*           cnt2    = (int*)(zbase + 128 * KB);          //  64 KB
  int*           cnt3    = (int*)(zbase + 192 * KB);          //  32 KB
  unsigned int*  bitmap0 = (unsigned int*)(zbase + 224 * KB); //   1 MB
  unsigned int*  bitmap1 = (unsigned int*)(zbase + 224 * KB + 1 * MB); // 256 KB
  float*         bnsum0  = (float*)(zbase + 480 * KB + 1 * MB);
  float*         bnsum1  = bnsum0 + 256;
  float*         bnsum2  = bnsum1 + 256;
  size_t zbytes = 480 * KB + 1 * MB + 3 * 256 * sizeof(float);

  hipMemsetAsync(zbase, 0, zbytes, stream);

  // ---------------- edge preprocessing for all 3 layers (feature-independent) ------------
  csr_count_all<<<256, 1024, 0, stream>>>(src0, dst0, cnt1, cnt2, cnt3,
                                          mask2, mask3, bitmap0, bitmap1);
  csr_scan3<<<96, 1024, 0, stream>>>(cnt1, cnt2, cnt3, rs1, rs2, rs3, pos1, pos2, pos3);
  csr_scatter_all<<<256, 1024, 0, stream>>>(src0, dst0, mask2, mask3,
                                            pos1, pos2, pos3, csr1, csr2, csr3);

  // ---------------- layer 1: M=32768, K=64, ids at shift 0 ----------------
  gemm_attn<64><<<1024, 256, 0, stream>>>(x0, W0, nullptr, 0.f, attS, attD, Hbuf, es, ed);
  gat_pool<<<8192, 256, 0, stream>>>(Hbuf, es, ed, csr1, rs1, cnt1, bias, Xbuf, 32768);
  bn_stats<<<128, 256, 0, stream>>>(Xbuf, bnsum0, 16384);

  // ---------------- layer 2: M=16384, K=128, ids at shift 1 ----------------
  gemm_attn<128><<<512, 256, 0, stream>>>(Xbuf, W1, bnsum0, 1.f / 16384.f,
                                          attS + 128, attD + 128, Hbuf, es, ed);
  gat_pool<<<4096, 256, 0, stream>>>(Hbuf, es, ed, csr2, rs2, cnt2, bias + 128, Xbuf, 16384);
  bn_stats<<<128, 256, 0, stream>>>(Xbuf, bnsum1, 8192);

  // ---------------- layer 3: M=8192, K=128, ids at shift 2 ----------------
  gemm_attn<128><<<256, 256, 0, stream>>>(Xbuf, W2, bnsum1, 1.f / 8192.f,
                                          attS + 256, attD + 256, Hbuf, es, ed);
  gat_pool<<<2048, 256, 0, stream>>>(Hbuf, es, ed, csr3, rs3, cnt3, bias + 256, Xbuf, 8192);
  bn_stats<<<128, 256, 0, stream>>>(Xbuf, bnsum2, 4096);
  bn_norm<<<2048, 256, 0, stream>>>(Xbuf, bnsum2, out, 4096);
}

// Round 2
// 240.701 us; speedup vs baseline: 1.1420x; 1.1420x over previous
//
#include <hip/hip_runtime.h>

// Problem constants: B=32 graphs, N=1024 nodes/graph, F=64, D=128, DEG=8
#define E_TOTAL 262144     // B*N*DEG
#define NGRAPH  32
#define EPG     8192       // edges per graph
#define EPS_BN  1e-5f
#define MB (1u << 20)
#define KB (1u << 10)

__device__ __forceinline__ float lrelu(float x){ return x > 0.f ? x : 0.2f * x; }

// XCD-aware block swizzle (neutral in r1 but harmless; keeps graph locality per XCD).
__device__ __forceinline__ int xcd_swz(int b, int n){ return (b & 7) * (n >> 3) + (b >> 3); }

// ---------------- GEMM + attention terms: C = bn(A) @ W, es = C.a_s, ed = C.a_d ----------
// block 256 = 64 channel-pairs x 4 row-groups (one wave per row-group); 32 rows/block.
// A tile staged TRANSPOSED in LDS (stride 36 => aligned float4 broadcast reads).
// bnsums != nullptr: normalize A columns with batch stats (sums[c], sums[K+c]).
template<int K>
__global__ __launch_bounds__(256)
void gemm_attn(const float* __restrict__ A, const float* __restrict__ W,
               const float* __restrict__ bnsums, float invM,
               const float* __restrict__ a_s, const float* __restrict__ a_d,
               float* __restrict__ C, float* __restrict__ es, float* __restrict__ ed){
  __shared__ float Ws[64 * 128];    // 32 KB
  __shared__ float As_t[64 * 36];   // 9 KB, [kk][row] padded
  __shared__ float bnmu[K], bnrs[K];
  int tid = threadIdx.x;
  if (tid < K){
    float mu = 0.f, rs = 1.f;
    if (bnsums){
      mu = bnsums[tid] * invM;
      float var = bnsums[K + tid] * invM - mu * mu;
      rs = rsqrtf(var + EPS_BN);
    }
    bnmu[tid] = mu; bnrs[tid] = rs;
  }
  int bid = xcd_swz(blockIdx.x, gridDim.x);
  int row0 = bid * 32;
  int c2 = tid & 63, rg = tid >> 6;
  float2 acc[8];
  #pragma unroll
  for (int i = 0; i < 8; ++i){ acc[i].x = 0.f; acc[i].y = 0.f; }

  for (int k0 = 0; k0 < K; k0 += 64){
    __syncthreads();
    for (int i = tid; i < 64 * 128; i += 256)
      Ws[i] = W[(size_t)(k0 + (i >> 7)) * 128 + (i & 127)];
    #pragma unroll
    for (int it = 0; it < 8; ++it){
      int i = it * 256 + tid;
      int r = i >> 6, kk = i & 63;
      float v = A[(size_t)(row0 + r) * K + k0 + kk];
      v = (v - bnmu[k0 + kk]) * bnrs[k0 + kk];
      As_t[kk * 36 + r] = v;
    }
    __syncthreads();
    #pragma unroll 8
    for (int kk = 0; kk < 64; ++kk){
      float2 w = *(float2*)&Ws[kk * 128 + c2 * 2];
      float4 a0 = *(float4*)&As_t[kk * 36 + rg * 8];
      float4 a1 = *(float4*)&As_t[kk * 36 + rg * 8 + 4];
      acc[0].x = fmaf(a0.x, w.x, acc[0].x); acc[0].y = fmaf(a0.x, w.y, acc[0].y);
      acc[1].x = fmaf(a0.y, w.x, acc[1].x); acc[1].y = fmaf(a0.y, w.y, acc[1].y);
      acc[2].x = fmaf(a0.z, w.x, acc[2].x); acc[2].y = fmaf(a0.z, w.y, acc[2].y);
      acc[3].x = fmaf(a0.w, w.x, acc[3].x); acc[3].y = fmaf(a0.w, w.y, acc[3].y);
      acc[4].x = fmaf(a1.x, w.x, acc[4].x); acc[4].y = fmaf(a1.x, w.y, acc[4].y);
      acc[5].x = fmaf(a1.y, w.x, acc[5].x); acc[5].y = fmaf(a1.y, w.y, acc[5].y);
      acc[6].x = fmaf(a1.z, w.x, acc[6].x); acc[6].y = fmaf(a1.z, w.y, acc[6].y);
      acc[7].x = fmaf(a1.w, w.x, acc[7].x); acc[7].y = fmaf(a1.w, w.y, acc[7].y);
    }
  }
  float2 as2 = ((const float2*)a_s)[c2];
  float2 ad2 = ((const float2*)a_d)[c2];
  float2* C2 = (float2*)C;
  #pragma unroll
  for (int i = 0; i < 8; ++i){
    int r = row0 + rg * 8 + i;
    C2[(size_t)r * 64 + c2] = acc[i];
    float e1 = acc[i].x * as2.x + acc[i].y * as2.y;
    float e2 = acc[i].x * ad2.x + acc[i].y * ad2.y;
    #pragma unroll
    for (int o = 32; o; o >>= 1){ e1 += __shfl_xor(e1, o); e2 += __shfl_xor(e2, o); }
    if (c2 == 0){ es[r] = e1; ed[r] = e2; }
  }
}

// ---------------- CSR build, ALL layers, ONE kernel, one block per graph ----------------
// Pass 1: count histograms for L1/L2/L3 with dedupe via LDS bitmaps (32KB + 8KB),
//         keep-masks held in registers (8 edges/thread).
// Scan:   in-block exclusive scans (1024/512/256) -> global row_start + row_cnt,
//         LDS histograms become scatter cursors.
// Pass 2: scatter src ids into csr1/csr2/csr3.
// Dedupe tie-breaking differs from a sort-based approach but the surviving edge SET is
// identical, which is all the GAT softmax depends on. Block 0 also zeroes bnsums (768 f).
__global__ __launch_bounds__(1024)
void csr_build_all(const int* __restrict__ src0, const int* __restrict__ dst0,
                   int* __restrict__ csr1, int* __restrict__ csr2, int* __restrict__ csr3,
                   int* __restrict__ rs1, int* __restrict__ rs2, int* __restrict__ rs3,
                   int* __restrict__ cnt1, int* __restrict__ cnt2, int* __restrict__ cnt3,
                   float* __restrict__ bnsums){
  __shared__ unsigned int bm2[8192];   // 512*512 pair bits = 32 KB
  __shared__ unsigned int bm3[2048];   // 256*256 pair bits =  8 KB
  __shared__ int h1[1024];
  __shared__ int h2[512];
  __shared__ int h3[256];
  __shared__ int wsum[16];
  int g = blockIdx.x, t = threadIdx.x;
  int ebase = g * EPG;
  if (g == 0 && t < 768) bnsums[t] = 0.f;
  #pragma unroll
  for (int i = t; i < 8192; i += 1024) bm2[i] = 0u;
  #pragma unroll
  for (int i = t; i < 2048; i += 1024) bm3[i] = 0u;
  h1[t] = 0;
  if (t < 512) h2[t] = 0;
  if (t < 256) h3[t] = 0;
  __syncthreads();

  // ---- pass 1: count + dedupe, masks in registers ----
  unsigned int k1 = 0, k2 = 0, k3 = 0;
  #pragma unroll
  for (int k = 0; k < 8; ++k){
    int e = ebase + k * 1024 + t;
    int sv = src0[e], dv = dst0[e];
    if (sv != dv){
      k1 |= 1u << k;
      atomicAdd(&h1[dv & 1023], 1);
      int s2 = (sv >> 1) & 511, d2 = (dv >> 1) & 511;
      if (s2 != d2){
        int key = (s2 << 9) | d2;
        unsigned int bit = 1u << (key & 31);
        unsigned int old = atomicOr(&bm2[key >> 5], bit);
        if (!(old & bit)){
          k2 |= 1u << k;
          atomicAdd(&h2[d2], 1);
          int s3 = (sv >> 2) & 255, d3 = (dv >> 2) & 255;
          if (s3 != d3){
            int key3 = (s3 << 8) | d3;
            unsigned int b3 = 1u << (key3 & 31);
            unsigned int o3 = atomicOr(&bm3[key3 >> 5], b3);
            if (!(o3 & b3)){ k3 |= 1u << k; atomicAdd(&h3[d3], 1); }
          }
        }
      }
    }
  }
  __syncthreads();

  int lane = t & 63, w = t >> 6;
  // ---- scan L1 (1024 counters) ----
  {
    int c = h1[t], v = c;
    #pragma unroll
    for (int o = 1; o < 64; o <<= 1){ int u = __shfl_up(v, o); if (lane >= o) v += u; }
    if (lane == 63) wsum[w] = v;
    __syncthreads();
    if (t == 0){ int run = 0;
      #pragma unroll
      for (int i = 0; i < 16; ++i){ int x = wsum[i]; wsum[i] = run; run += x; } }
    __syncthreads();
    int excl = v - c + wsum[w];
    cnt1[(g << 10) + t] = c;
    rs1 [(g << 10) + t] = ebase + excl;
    h1[t] = excl;
  }
  __syncthreads();
  // ---- scan L2 (512 counters) ----
  {
    int c = (t < 512) ? h2[t] : 0, v = c;
    #pragma unroll
    for (int o = 1; o < 64; o <<= 1){ int u = __shfl_up(v, o); if (lane >= o) v += u; }
    if (lane == 63) wsum[w] = v;
    __syncthreads();
    if (t == 0){ int run = 0;
      #pragma unroll
      for (int i = 0; i < 16; ++i){ int x = wsum[i]; wsum[i] = run; run += x; } }
    __syncthreads();
    int excl = v - c + wsum[w];
    if (t < 512){
      cnt2[(g << 9) + t] = c;
      rs2 [(g << 9) + t] = ebase + excl;
      h2[t] = excl;
    }
  }
  __syncthreads();
  // ---- scan L3 (256 counters) ----
  {
    int c = (t < 256) ? h3[t] : 0, v = c;
    #pragma unroll
    for (int o = 1; o < 64; o <<= 1){ int u = __shfl_up(v, o); if (lane >= o) v += u; }
    if (lane == 63) wsum[w] = v;
    __syncthreads();
    if (t == 0){ int run = 0;
      #pragma unroll
      for (int i = 0; i < 16; ++i){ int x = wsum[i]; wsum[i] = run; run += x; } }
    __syncthreads();
    int excl = v - c + wsum[w];
    if (t < 256){
      cnt3[(g << 8) + t] = c;
      rs3 [(g << 8) + t] = ebase + excl;
      h3[t] = excl;
    }
  }
  __syncthreads();

  // ---- pass 2: scatter (LDS cursors) ----
  unsigned int any = k1 | k2 | k3;
  #pragma unroll
  for (int k = 0; k < 8; ++k){
    if ((any >> k) & 1u){
      int e = ebase + k * 1024 + t;
      int sv = src0[e], dv = dst0[e];
      if ((k1 >> k) & 1u){
        int p = atomicAdd(&h1[dv & 1023], 1);
        csr1[ebase + p] = sv;
      }
      if ((k2 >> k) & 1u){
        int p = atomicAdd(&h2[(dv >> 1) & 511], 1);
        csr2[ebase + p] = sv >> 1;
      }
      if ((k3 >> k) & 1u){
        int p = atomicAdd(&h3[(dv >> 2) & 255], 1);
        csr3[ebase + p] = sv >> 2;
      }
    }
  }
}

// ---------------- GAT softmax-aggregate + bias + ReLU + pairwise max-pool ----------------
// one wave per dst node; block 256 -> nodes 4b..4b+3 = pool pairs; writes M/2 pooled rows.
// Phase A caches the first 64 (src, logit) per lane in registers so phase B skips the
// redundant csr+es re-gather for rows with cnt<=64 (all rows in this data; generic
// fallback keeps correctness for larger rows).
__global__ void gat_pool(const float* __restrict__ h, const float* __restrict__ es,
                         const float* __restrict__ ed, const int* __restrict__ csr_src,
                         const int* __restrict__ row_start, const int* __restrict__ row_cnt,
                         const float* __restrict__ bias, float* __restrict__ xout, int M){
  __shared__ float2 osh[4][64];
  int lane = threadIdx.x & 63;
  int wave = threadIdx.x >> 6;
  int bid = xcd_swz(blockIdx.x, gridDim.x);
  int n = bid * 4 + wave;
  int start = row_start[n];
  int cnt   = row_cnt[n];
  float edn = ed[n];
  float selfl = lrelu(es[n] + edn);

  // phase A: online softmax stats, lane-parallel; cache first chunk in regs
  float m_l = -1e30f, d_l = 0.f;
  int   s_c = 0; float l_c = 0.f;
  for (int c0 = 0; c0 < cnt; c0 += 64){
    int j = c0 + lane;
    if (j < cnt){
      int s = csr_src[start + j];
      float l = lrelu(es[s] + edn);
      if (c0 == 0){ s_c = s; l_c = l; }
      float mn = fmaxf(m_l, l);
      d_l = d_l * __expf(m_l - mn) + __expf(l - mn);
      m_l = mn;
    }
  }
  #pragma unroll
  for (int o = 32; o; o >>= 1){
    float m2 = __shfl_xor(m_l, o), d2 = __shfl_xor(d_l, o);
    float mn = fmaxf(m_l, m2);
    d_l = d_l * __expf(m_l - mn) + d2 * __expf(m2 - mn);
    m_l = mn;
  }
  float mf  = fmaxf(m_l, selfl);
  float den = d_l * __expf(m_l - mf) + __expf(selfl - mf);

  // phase B: weighted accumulation, 8 gathers in flight via shfl-broadcast indices
  const float2* h2 = (const float2*)h;
  float sw = __expf(selfl - mf);
  float2 hv = h2[(size_t)n * 64 + lane];
  float2 acc; acc.x = sw * hv.x; acc.y = sw * hv.y;
  for (int c0 = 0; c0 < cnt; c0 += 64){
    int j = c0 + lane;
    int s_j; float w_j;
    if (c0 == 0){
      s_j = s_c;
      w_j = (lane < cnt) ? __expf(l_c - mf) : 0.f;
    } else {
      s_j = 0; w_j = 0.f;
      if (j < cnt){
        s_j = csr_src[start + j];
        w_j = __expf(lrelu(es[s_j] + edn) - mf);
      }
    }
    int rem = min(64, cnt - c0);
    int k = 0;
    for (; k + 8 <= rem; k += 8){
      int ss[8]; float ww[8]; float2 hh[8];
      #pragma unroll
      for (int i = 0; i < 8; ++i){ ss[i] = __shfl(s_j, k + i); ww[i] = __shfl(w_j, k + i); }
      #pragma unroll
      for (int i = 0; i < 8; ++i){ hh[i] = h2[(size_t)ss[i] * 64 + lane]; }
      #pragma unroll
      for (int i = 0; i < 8; ++i){
        acc.x = fmaf(ww[i], hh[i].x, acc.x);
        acc.y = fmaf(ww[i], hh[i].y, acc.y);
      }
    }
    for (; k < rem; ++k){
      int s = __shfl(s_j, k); float w = __shfl(w_j, k);
      float2 hh = h2[(size_t)s * 64 + lane];
      acc.x = fmaf(w, hh.x, acc.x);
      acc.y = fmaf(w, hh.y, acc.y);
    }
  }
  float inv = 1.f / den;
  float2 bv = ((const float2*)bias)[lane];
  float2 o2;
  o2.x = fmaxf(acc.x * inv + bv.x, 0.f);
  o2.y = fmaxf(acc.y * inv + bv.y, 0.f);
  osh[wave][lane] = o2;
  __syncthreads();
  if (wave < 2){
    float2 a = osh[2 * wave][lane], b = osh[2 * wave + 1][lane];
    float2 p; p.x = fmaxf(a.x, b.x); p.y = fmaxf(a.y, b.y);
    ((float2*)xout)[(size_t)(bid * 2 + wave) * 64 + lane] = p;
  }
}

// ---------------- BN stats over pooled X (bnsums zeroed by csr_build_all) ----------------
__global__ void bn_stats(const float* __restrict__ x, float* __restrict__ sums, int M){
  __shared__ float s1[256], s2[256];
  int c = threadIdx.x & 127, half = threadIdx.x >> 7;
  float a = 0.f, b = 0.f;
  for (int r = blockIdx.x * 2 + half; r < M; r += 256){
    float v = x[(size_t)r * 128 + c];
    a += v; b += v * v;
  }
  s1[threadIdx.x] = a; s2[threadIdx.x] = b;
  __syncthreads();
  if (threadIdx.x < 128){
    atomicAdd(&sums[c],       s1[threadIdx.x] + s1[threadIdx.x + 128]);
    atomicAdd(&sums[128 + c], s2[threadIdx.x] + s2[threadIdx.x + 128]);
  }
}

// ---------------- final BatchNorm apply ----------------
__global__ void bn_norm(const float* __restrict__ in, const float* __restrict__ sums,
                        float* __restrict__ out, int M){
  int idx = blockIdx.x * blockDim.x + threadIdx.x;
  if (idx >= M * 128) return;
  int c = idx & 127;
  float mu  = sums[c] / (float)M;
  float var = sums[128 + c] / (float)M - mu * mu;
  out[idx] = (in[idx] - mu) * rsqrtf(var + EPS_BN);
}

extern "C" void kernel_launch(void* const* d_in, const int* in_sizes, int n_in,
                              void* d_out, int out_size, void* d_ws, size_t ws_size,
                              hipStream_t stream){
  const float* x0   = (const float*)d_in[0];
  const float* W0   = (const float*)d_in[1];
  const float* W1   = (const float*)d_in[2];
  const float* W2   = (const float*)d_in[3];
  const float* attS = (const float*)d_in[4];
  const float* attD = (const float*)d_in[5];
  const float* bias = (const float*)d_in[6];
  const int*   src0 = (const int*)d_in[7];
  const int*   dst0 = src0 + E_TOTAL;
  float* out = (float*)d_out;                  // (32, 16384) f32

  char* ws = (char*)d_ws;
  float* Hbuf   = (float*)(ws);                        // 16 MB
  float* Xbuf   = (float*)(ws + 16 * MB);              //  8 MB (pooled)
  int*   csr1   = (int*)  (ws + 24 * MB);              //  1 MB
  int*   csr2   = (int*)  (ws + 25 * MB);              //  1 MB
  int*   csr3   = (int*)  (ws + 26 * MB);              //  1 MB
  float* es     = (float*)(ws + 27 * MB);              // 128 KB
  float* ed     = (float*)(ws + 27 * MB + 128 * KB);   // 128 KB
  int*   rs1    = (int*)  (ws + 27 * MB + 256 * KB);   // 128 KB
  int*   rs2    = (int*)  (ws + 27 * MB + 384 * KB);   //  64 KB
  int*   rs3    = (int*)  (ws + 27 * MB + 448 * KB);   //  32 KB
  int*   cnt1   = (int*)  (ws + 27 * MB + 480 * KB);   // 128 KB
  int*   cnt2   = (int*)  (ws + 27 * MB + 608 * KB);   //  64 KB
  int*   cnt3   = (int*)  (ws + 27 * MB + 672 * KB);   //  32 KB
  float* bnsum0 = (float*)(ws + 27 * MB + 704 * KB);   // 768 floats total
  float* bnsum1 = bnsum0 + 256;
  float* bnsum2 = bnsum1 + 256;

  // ---------------- edge preprocessing: one kernel, all 3 layers, no memset --------------
  csr_build_all<<<NGRAPH, 1024, 0, stream>>>(src0, dst0, csr1, csr2, csr3,
                                             rs1, rs2, rs3, cnt1, cnt2, cnt3, bnsum0);

  // ---------------- layer 1: M=32768, K=64 ----------------
  gemm_attn<64><<<1024, 256, 0, stream>>>(x0, W0, nullptr, 0.f, attS, attD, Hbuf, es, ed);
  gat_pool<<<8192, 256, 0, stream>>>(Hbuf, es, ed, csr1, rs1, cnt1, bias, Xbuf, 32768);
  bn_stats<<<128, 256, 0, stream>>>(Xbuf, bnsum0, 16384);

  // ---------------- layer 2: M=16384, K=128 ----------------
  gemm_attn<128><<<512, 256, 0, stream>>>(Xbuf, W1, bnsum0, 1.f / 16384.f,
                                          attS + 128, attD + 128, Hbuf, es, ed);
  gat_pool<<<4096, 256, 0, stream>>>(Hbuf, es, ed, csr2, rs2, cnt2, bias + 128, Xbuf, 16384);
  bn_stats<<<128, 256, 0, stream>>>(Xbuf, bnsum1, 8192);

  // ---------------- layer 3: M=8192, K=128 ----------------
  gemm_attn<128><<<256, 256, 0, stream>>>(Xbuf, W2, bnsum1, 1.f / 8192.f,
                                          attS + 256, attD + 256, Hbuf, es, ed);
  gat_pool<<<2048, 256, 0, stream>>>(Hbuf, es, ed, csr3, rs3, cnt3, bias + 256, Xbuf, 8192);
  bn_stats<<<128, 256, 0, stream>>>(Xbuf, bnsum2, 4096);
  bn_norm<<<2048, 256, 0, stream>>>(Xbuf, bnsum2, out, 4096);
}